// Round 13
// baseline (687.798 us; speedup 1.0000x reference)
//
#include <hip/hip_runtime.h>
#include <hip/hip_bf16.h>
#include <math.h>

#define N_NODES 50000
#define MP      50048  // padded to 128-row multiple for async-staged GEMM A reads
#define N_EDGES 800000
#define F_IN    165
#define KPAD1   192   // F_IN padded to multiple of 32
#define D1      256   // 8 heads x 32
#define D3      128   // 4 heads x 32
#define CAP     64    // max edges per node (Poisson(16): P(deg>=64) ~ 1e-19)

typedef __attribute__((ext_vector_type(8))) short short8;   // 8 bf16 = 4 VGPRs
typedef __attribute__((ext_vector_type(4))) float floatx4;
typedef __attribute__((ext_vector_type(2))) float floatx2;

__device__ __forceinline__ float bflo(unsigned u) { return __uint_as_float(u << 16); }
__device__ __forceinline__ float bfhi(unsigned u) { return __uint_as_float(u & 0xffff0000u); }

// packed-fp32 scale-accumulate: 8 bf16 lanes -> 4 v_pk_fma_f32
__device__ __forceinline__ void fma8p(floatx2* a, float wgt, const uint4& v) {
    floatx2 w2; w2.x = wgt; w2.y = wgt;
    floatx2 p;
    p.x = bflo(v.x); p.y = bfhi(v.x); a[0] += w2 * p;
    p.x = bflo(v.y); p.y = bfhi(v.y); a[1] += w2 * p;
    p.x = bflo(v.z); p.y = bfhi(v.z); a[2] += w2 * p;
    p.x = bflo(v.w); p.y = bfhi(v.w); a[3] += w2 * p;
}

#if defined(__has_builtin)
#if __has_builtin(__builtin_amdgcn_global_load_lds)
#define HAS_GLL 1
#endif
#endif

__device__ __forceinline__ void gload16(const void* g, void* lds) {
#ifdef HAS_GLL
    __builtin_amdgcn_global_load_lds(
        (const __attribute__((address_space(1))) unsigned*)g,
        (__attribute__((address_space(3))) unsigned*)lds, 16, 0, 0);
#else
    *(int4*)lds = *(const int4*)g;
#endif
}

// ---------- fused prep + degree histogram ----------
// idx < E: degree histogram. Else prep (shifted by E):
// xb [MP x KPAD1]; Bt1 [512 x KPAD1] (W1^T | skW^T | 16 attn rows);
// Bt2 [384 x D1] (W2^T | 16 attn rows); Bt3 [256 x D1] (W3^T | 8 attn rows).
__global__ void prep_hist(const int* __restrict__ ei, int* __restrict__ deg,
                          const float* __restrict__ x, __hip_bfloat16* __restrict__ xb,
                          const float* __restrict__ W1, const float* __restrict__ skW,
                          const float* __restrict__ a1s, const float* __restrict__ a1d,
                          __hip_bfloat16* __restrict__ Bt1,
                          const float* __restrict__ W2,
                          const float* __restrict__ a2s, const float* __restrict__ a2d,
                          __hip_bfloat16* __restrict__ Bt2,
                          const float* __restrict__ W3,
                          const float* __restrict__ a3s, const float* __restrict__ a3d,
                          __hip_bfloat16* __restrict__ Bt3)
{
    long long gidx = (long long)blockIdx.x * 256 + threadIdx.x;
    if (gidx < N_EDGES) {
        atomicAdd(&deg[ei[N_EDGES + gidx]], 1);
        return;
    }
    long long idx = gidx - N_EDGES;
    const long long S0 = (long long)MP * KPAD1;          // xb
    const long long S1 = S0 + 256 * KPAD1;               // Wt1 rows
    const long long S2 = S1 + 128 * KPAD1;               // skWt rows
    const long long S3 = S2 + 16 * KPAD1;                // Wa1 rows
    const long long S4 = S3 + 256 * D1;                  // Wt2 rows
    const long long S5 = S4 + 16 * D1;                   // Wa2 rows
    const long long S6 = S5 + 128 * D1;                  // Wt3 rows
    const long long S7 = S6 + 8 * D1;                    // Wa3 rows
    if (idx < S0) {
        const int m = idx / KPAD1, k = idx - (long long)m * KPAD1;
        xb[idx] = __float2bfloat16((k < F_IN && m < N_NODES) ? x[(size_t)m * F_IN + k] : 0.f);
    } else if (idx < S1) {
        const long long i = idx - S0;
        const int n = i / KPAD1, k = i - (long long)n * KPAD1;
        Bt1[(size_t)n * KPAD1 + k] = __float2bfloat16((k < F_IN) ? W1[(size_t)k * D1 + n] : 0.f);
    } else if (idx < S2) {
        const long long i = idx - S1;
        const int n = i / KPAD1, k = i - (long long)n * KPAD1;
        Bt1[(size_t)(256 + n) * KPAD1 + k] =
            __float2bfloat16((k < F_IN) ? skW[(size_t)k * D3 + n] : 0.f);
    } else if (idx < S3) {
        const long long i = idx - S2;
        const int r = i / KPAD1, k = i - (long long)r * KPAD1;   // r: 0-7 src, 8-15 dst
        const int hh = r & 7;
        const float* av = (r < 8) ? a1s : a1d;
        float s = 0.f;
        if (k < F_IN)
#pragma unroll
            for (int d = 0; d < 32; ++d) s += W1[(size_t)k * D1 + hh * 32 + d] * av[hh * 32 + d];
        Bt1[(size_t)(384 + r) * KPAD1 + k] = __float2bfloat16(s);
    } else if (idx < S4) {
        const long long i = idx - S3;
        const int n = i / D1, k = i - (long long)n * D1;
        Bt2[(size_t)n * D1 + k] = __float2bfloat16(W2[(size_t)k * D1 + n]);
    } else if (idx < S5) {
        const long long i = idx - S4;
        const int r = i / D1, k = i - (long long)r * D1;
        const int hh = r & 7;
        const float* av = (r < 8) ? a2s : a2d;
        float s = 0.f;
#pragma unroll
        for (int d = 0; d < 32; ++d) s += W2[(size_t)k * D1 + hh * 32 + d] * av[hh * 32 + d];
        Bt2[(size_t)(256 + r) * D1 + k] = __float2bfloat16(s);
    } else if (idx < S6) {
        const long long i = idx - S5;
        const int n = i / D1, k = i - (long long)n * D1;
        Bt3[(size_t)n * D1 + k] = __float2bfloat16(W3[(size_t)k * D3 + n]);
    } else if (idx < S7) {
        const long long i = idx - S6;
        const int r = i / D1, k = i - (long long)r * D1;
        const int hh = r & 3;
        const float* av = (r < 4) ? a3s : a3d;
        float s = 0.f;
#pragma unroll
        for (int d = 0; d < 32; ++d) s += W3[(size_t)k * D3 + hh * 32 + d] * av[hh * 32 + d];
        Bt3[(size_t)(128 + r) * D1 + k] = __float2bfloat16(s);
    }
}

// ---------- bf16 MFMA GEMM, internal n-tile loop (A fetched once, L2-reused) ----------
// Output columns: [0,Dh) -> Cb bf16; [Dh,Dh+Dx) -> Cx bf16 (+biasx);
// [Dh+Dx, Dh+Dx+H) -> asrc fp32; [.., +2H) -> adst fp32; >= NNlive discarded.
__global__ __launch_bounds__(256) void gemm_bf16(
    const __hip_bfloat16* __restrict__ A, const __hip_bfloat16* __restrict__ Bt,
    const float* __restrict__ alphap,
    __hip_bfloat16* __restrict__ Cb, int Dh,
    __hip_bfloat16* __restrict__ Cx, const float* __restrict__ biasx, int Dx,
    float* __restrict__ asrc, float* __restrict__ adst, int H,
    int M, int Ka, int NT)
{
    __shared__ short As[128 * 32];
    __shared__ short Bs[128 * 32];
    const int t  = threadIdx.x;
    const int m0 = blockIdx.x * 128;
    const int w  = t >> 6, l = t & 63;
    const int wy = w >> 1, wx = w & 1;
    const int lm = l & 15, quad = l >> 4;
    const float alpha = alphap ? alphap[0] : 1.f;
    const int NNlive = Dh + Dx + 2 * H;

    const int ch0 = w * 128 + l;
    const int ch1 = ch0 + 64;
    const int r0a = ch0 >> 2, k0a = (ch0 & 3) * 8;
    const int r1a = ch1 >> 2, k1a = (ch1 & 3) * 8;

    for (int nt = 0; nt < NT; ++nt) {
        const int n0 = nt * 128;
        floatx4 acc[4][4] = {};

        for (int k0 = 0; k0 < Ka; k0 += 32) {
            gload16(A  + (size_t)(m0 + r0a) * Ka + k0 + k0a, &As[ch0 * 8]);
            gload16(A  + (size_t)(m0 + r1a) * Ka + k0 + k1a, &As[ch1 * 8]);
            gload16(Bt + (size_t)(n0 + r0a) * Ka + k0 + k0a, &Bs[ch0 * 8]);
            gload16(Bt + (size_t)(n0 + r1a) * Ka + k0 + k1a, &Bs[ch1 * 8]);
            __syncthreads();

            short8 af[4], bf[4];
#pragma unroll
            for (int i = 0; i < 4; ++i) {
                af[i] = *(const short8*)&As[(wy * 64 + i * 16 + lm) * 32 + quad * 8];
                bf[i] = *(const short8*)&Bs[(wx * 64 + i * 16 + lm) * 32 + quad * 8];
            }
#pragma unroll
            for (int mi = 0; mi < 4; ++mi)
#pragma unroll
                for (int ni = 0; ni < 4; ++ni)
                    acc[mi][ni] = __builtin_amdgcn_mfma_f32_16x16x32_bf16(
                        af[mi], bf[ni], acc[mi][ni], 0, 0, 0);
            __syncthreads();
        }

        // epilogue: C/D layout col=lane&15, row=quad*4+reg
#pragma unroll
        for (int mi = 0; mi < 4; ++mi) {
#pragma unroll
            for (int r = 0; r < 4; ++r) {
                const int gm = m0 + wy * 64 + mi * 16 + quad * 4 + r;
                if (gm >= M) continue;
#pragma unroll
                for (int ni = 0; ni < 4; ++ni) {
                    const int gn = n0 + wx * 64 + ni * 16 + lm;
                    if (gn >= NNlive) continue;
                    const float v = acc[mi][ni][r] * alpha;
                    if (gn < Dh) {
                        Cb[(size_t)gm * Dh + gn] = __float2bfloat16(v);
                    } else if (gn < Dh + Dx) {
                        Cx[(size_t)gm * Dx + gn - Dh] = __float2bfloat16(v + biasx[gn - Dh]);
                    } else {
                        const int c = gn - Dh - Dx;
                        if (c < H) asrc[(size_t)gm * H + c] = v;
                        else       adst[(size_t)gm * H + c - H] = v;
                    }
                }
            }
        }
    }
}

// ---------- CSR build ----------
__global__ __launch_bounds__(1024) void scan_rowptr(const int* __restrict__ deg,
                                                    int* __restrict__ rowptr, int n)
{
    __shared__ int sums[1024];
    const int tid = threadIdx.x;
    const int chunk = (n + 1023) / 1024;
    const int lo = tid * chunk;
    const int hi = min(lo + chunk, n);
    int s = 0;
    for (int i = lo; i < hi; ++i) s += deg[i];
    sums[tid] = s;
    __syncthreads();
    for (int off = 1; off < 1024; off <<= 1) {
        int t = 0;
        if (tid >= off) t = sums[tid - off];
        __syncthreads();
        if (tid >= off) sums[tid] += t;
        __syncthreads();
    }
    int run = sums[tid] - s;
    for (int i = lo; i < hi; ++i) { rowptr[i] = run; run += deg[i]; }
    if (lo < n && hi == n) rowptr[n] = run;
}

__global__ void csr_fill(const int* __restrict__ ei, const int* __restrict__ rowptr,
                         int* __restrict__ cursor, int* __restrict__ csr_src, int E)
{
    const int e = blockIdx.x * blockDim.x + threadIdx.x;
    if (e >= E) return;
    const int dst = ei[E + e];
    const int pos = rowptr[dst] + atomicAdd(&cursor[dst], 1);
    csr_src[pos] = ei[e];
}

// ---------- fused GAT aggregation v9: wave/node, no-max softmax, 2 load streams ----------
// POST: 1 bias+BN+ELU -> bf16; 2 same + bf16 residual (in-place-safe) -> bf16;
//       3 final: +b3 +bf16 xinit -> FC(2) + log_softmax -> outF[N*2].
template <int HSH, int D, int POST>
__global__ __launch_bounds__(256) void gat_gather_v9(
    const __hip_bfloat16* __restrict__ h, const float* __restrict__ asrc,
    const float* __restrict__ adst, const int* __restrict__ rowptr,
    const int* __restrict__ csr_src, int selfloop,
    const float* __restrict__ bias, const float* __restrict__ g,
    const float* __restrict__ be, const float* __restrict__ mean,
    const float* __restrict__ var, const __hip_bfloat16* __restrict__ residB,
    const float* __restrict__ fcW, const float* __restrict__ fcb,
    float* __restrict__ outF, __hip_bfloat16* __restrict__ outB)
{
    constexpr int H    = 1 << HSH;
    constexpr int LPE  = D / 8;
    constexpr int EPW  = 64 / LPE;
    constexpr int SUBS = 64 >> HSH;
    constexpr int MAXJ = CAP / SUBS;

    const int w = threadIdx.x >> 6, l = threadIdx.x & 63;
    const int node = blockIdx.x * 4 + w;

    __shared__ float sW[4][CAP * H];
    __shared__ int   sSrc[4][CAP];

    const int r0  = rowptr[node];
    const int deg = rowptr[node + 1] - r0;
    const int tot = min(deg + selfloop, CAP);

    // ---- phase 1 (single pass): exp(leaky(logit)) -> sum -> pre-scaled weights ----
    const int hh  = l & (H - 1);
    const int sub = l >> HSH;
    const float ad = adst[node * H + hh];

    float ex[MAXJ];
    float sum = 0.f;
    {
        int nj = 0;
        for (int e = sub; e < tot; e += SUBS, ++nj) {
            const int s = (e < deg) ? csr_src[r0 + e] : node;
            if (hh == 0) sSrc[w][e] = s;
            float v = asrc[s * H + hh] + ad;
            v = v > 0.f ? v : 0.2f * v;
            ex[nj] = __expf(v);
            sum += ex[nj];
        }
    }
#pragma unroll
    for (int off = H; off < 64; off <<= 1) sum += __shfl_xor(sum, off);
    const float rs = 1.f / (sum + 1e-16f);
    {
        int nj = 0;
        for (int e = sub; e < tot; e += SUBS, ++nj)
            sW[w][e * H + hh] = ex[nj] * rs;
    }

    // ---- phase 2: weighted bf16 row gather, 2 streams, packed fp32 ----
    const int sw   = l / LPE;
    const int lo   = l % LPE;
    const int dimb = lo * 8;
    const int hh2  = dimb >> 5;
    floatx2 a0[4] = {}, a1[4] = {};

    for (int e = sw; e < tot; e += 2 * EPW) {
        const int e2  = e + EPW;
        const bool v2 = e2 < tot;
        const int sa = sSrc[w][e];
        const int sb = v2 ? sSrc[w][e2] : node;
        const float wa = sW[w][e * H + hh2];
        const float wb = v2 ? sW[w][e2 * H + hh2] : 0.f;
        const uint4 qa = *(const uint4*)&h[(size_t)sa * D + dimb];
        const uint4 qb = *(const uint4*)&h[(size_t)sb * D + dimb];
        fma8p(a0, wa, qa);
        fma8p(a1, wb, qb);
    }
    float acc[8];
#pragma unroll
    for (int v = 0; v < 4; ++v) {
        const floatx2 s2v = a0[v] + a1[v];
        acc[v * 2] = s2v.x; acc[v * 2 + 1] = s2v.y;
    }
#pragma unroll
    for (int off = LPE; off < 64; off <<= 1)
#pragma unroll
        for (int v = 0; v < 8; ++v) acc[v] += __shfl_xor(acc[v], off);

    // ---- epilogue ----
    if (POST == 3) {
        float v0 = 0.f, v1 = 0.f;
        if (l < LPE) {
            const uint4 rv = *(const uint4*)&residB[(size_t)node * D + dimb];
            const float rr[8] = {bflo(rv.x), bfhi(rv.x), bflo(rv.y), bfhi(rv.y),
                                 bflo(rv.z), bfhi(rv.z), bflo(rv.w), bfhi(rv.w)};
#pragma unroll
            for (int v = 0; v < 8; ++v) {
                const float val = acc[v] + bias[dimb + v] + rr[v];
                v0 += val * fcW[(dimb + v) * 2 + 0];
                v1 += val * fcW[(dimb + v) * 2 + 1];
            }
        }
#pragma unroll
        for (int off = 1; off < LPE; off <<= 1) {
            v0 += __shfl_xor(v0, off);
            v1 += __shfl_xor(v1, off);
        }
        if (l == 0) {
            const float l0 = v0 + fcb[0], l1 = v1 + fcb[1];
            const float m2 = fmaxf(l0, l1);
            const float lse = m2 + logf(__expf(l0 - m2) + __expf(l1 - m2));
            outF[node * 2 + 0] = l0 - lse;
            outF[node * 2 + 1] = l1 - lse;
        }
    } else {
        if (l < LPE) {
            float rr[8] = {};
            if (POST == 2) {
                const uint4 rv = *(const uint4*)&residB[(size_t)node * D + dimb];
                rr[0] = bflo(rv.x); rr[1] = bfhi(rv.x);
                rr[2] = bflo(rv.y); rr[3] = bfhi(rv.y);
                rr[4] = bflo(rv.z); rr[5] = bfhi(rv.z);
                rr[6] = bflo(rv.w); rr[7] = bfhi(rv.w);
            }
            __hip_bfloat16 rb[8];
#pragma unroll
            for (int v = 0; v < 8; ++v) {
                const int f = dimb + v;
                float vv = acc[v] + bias[f];
                vv = (vv - mean[f]) * rsqrtf(var[f] + 1e-5f) * g[f] + be[f];
                if (POST == 2) vv += rr[v];
                vv = vv > 0.f ? vv : (__expf(vv) - 1.f);
                rb[v] = __float2bfloat16(vv);
            }
            *(uint4*)&outB[(size_t)node * D + dimb] = *(uint4*)&rb[0];
        }
    }
}

extern "C" void kernel_launch(void* const* d_in, const int* in_sizes, int n_in,
                              void* d_out, int out_size, void* d_ws, size_t ws_size,
                              hipStream_t stream)
{
    const float* x    = (const float*)d_in[0];
    const int*   ei   = (const int*)  d_in[1];
    const float* W1   = (const float*)d_in[2];
    const float* a1s  = (const float*)d_in[3];
    const float* a1d  = (const float*)d_in[4];
    const float* b1   = (const float*)d_in[5];
    const float* g1   = (const float*)d_in[6];
    const float* be1  = (const float*)d_in[7];
    const float* m1   = (const float*)d_in[8];
    const float* v1   = (const float*)d_in[9];
    const float* W2   = (const float*)d_in[10];
    const float* a2s  = (const float*)d_in[11];
    const float* a2d  = (const float*)d_in[12];
    const float* b2   = (const float*)d_in[13];
    const float* g2   = (const float*)d_in[14];
    const float* be2  = (const float*)d_in[15];
    const float* m2   = (const float*)d_in[16];
    const float* v2   = (const float*)d_in[17];
    const float* W3   = (const float*)d_in[18];
    const float* a3s  = (const float*)d_in[19];
    const float* a3d  = (const float*)d_in[20];
    const float* b3   = (const float*)d_in[21];
    const float* fcW  = (const float*)d_in[22];
    const float* fcb  = (const float*)d_in[23];
    const float* skW  = (const float*)d_in[24];
    const float* skb  = (const float*)d_in[25];
    const float* temp = (const float*)d_in[26];

    float* out = (float*)d_out;

    const int N = N_NODES, E = N_EDGES;

    // workspace layout (float units)
    float* ws = (float*)d_ws;
    size_t o = 0;
    float* asrc  = ws + o;  o += (size_t)N * 8;
    float* adst  = ws + o;  o += (size_t)N * 8;
    int* rowptr  = (int*)(ws + o);  o += N + 1;
    o = (o + 3) & ~(size_t)3;
    int* csr_src = (int*)(ws + o);  o += E;
    o = (o + 3) & ~(size_t)3;
    __hip_bfloat16* xb     = (__hip_bfloat16*)(ws + o); o += (size_t)MP * KPAD1 / 2;
    __hip_bfloat16* bufCb  = (__hip_bfloat16*)(ws + o); o += (size_t)MP * D1 / 2;  // layer input / residual
    __hip_bfloat16* hb     = (__hip_bfloat16*)(ws + o); o += (size_t)N * D1 / 2;   // GEMM out
    __hip_bfloat16* xinitB = (__hip_bfloat16*)(ws + o); o += (size_t)N * D3 / 2;   // skip branch bf16
    __hip_bfloat16* Bt1    = (__hip_bfloat16*)(ws + o); o += (size_t)512 * KPAD1 / 2;
    __hip_bfloat16* Bt2    = (__hip_bfloat16*)(ws + o); o += (size_t)384 * D1 / 2;
    __hip_bfloat16* Bt3    = (__hip_bfloat16*)(ws + o); o += (size_t)256 * D1 / 2;
    int* deg    = (int*)hb;        // alias: CSR build finishes before hb's first write
    int* cursor = deg + N;

    const int MT128 = MP / 128;      // 391

    // ---- CSR build + fused prep ----
    hipMemsetAsync(deg, 0, (size_t)2 * N * sizeof(int), stream);
    {
        const long long tote = (long long)E + (long long)MP * KPAD1 +
                               (256 + 128 + 16) * (long long)KPAD1 +
                               (256 + 16 + 128 + 8) * (long long)D1;
        prep_hist<<<(tote + 255) / 256, 256, 0, stream>>>(
            ei, deg, x, xb, W1, skW, a1s, a1d, Bt1, W2, a2s, a2d, Bt2, W3, a3s, a3d, Bt3);
    }
    scan_rowptr<<<1, 1024, 0, stream>>>(deg, rowptr, N);
    csr_fill<<<(E + 255) / 256, 256, 0, stream>>>(ei, rowptr, cursor, csr_src, E);

    // ================= Layer 1 GEMM: h1 | xinit | asrc | adst (live cols = 400) =================
    gemm_bf16<<<MT128, 256, 0, stream>>>(xb, Bt1, nullptr,
                                         hb, D1, xinitB, skb, D3,
                                         asrc, adst, 8, N, KPAD1, 4);
    gat_gather_v9<3, D1, 1><<<N / 4, 256, 0, stream>>>(hb, asrc, adst, rowptr, csr_src, 0,
                                                       b1, g1, be1, m1, v1, nullptr, nullptr, nullptr,
                                                       nullptr, bufCb);

    // ================= Layer 2 GEMM: h2 | asrc | adst (live cols = 272) =================
    gemm_bf16<<<MT128, 256, 0, stream>>>(bufCb, Bt2, nullptr,
                                         hb, D1, nullptr, nullptr, 0,
                                         asrc, adst, 8, N, D1, 3);
    gat_gather_v9<3, D1, 2><<<N / 4, 256, 0, stream>>>(hb, asrc, adst, rowptr, csr_src, 1,
                                                       b2, g2, be2, m2, v2, bufCb, nullptr, nullptr,
                                                       nullptr, bufCb);

    // ================= Layer 3 GEMM (temp-scaled): h3 | asrc | adst (live = 136) =================
    gemm_bf16<<<MT128, 256, 0, stream>>>(bufCb, Bt3, temp,
                                         hb, D3, nullptr, nullptr, 0,
                                         asrc, adst, 4, N, D1, 2);
    gat_gather_v9<2, D3, 3><<<N / 4, 256, 0, stream>>>(hb, asrc, adst, rowptr, csr_src, 1,
                                                       b3, nullptr, nullptr, nullptr, nullptr, xinitB,
                                                       fcW, fcb, out, nullptr);

    (void)in_sizes; (void)n_in; (void)out_size; (void)ws_size;
}

// Round 14
// 604.302 us; speedup vs baseline: 1.1382x; 1.1382x over previous
//
#include <hip/hip_runtime.h>
#include <hip/hip_bf16.h>
#include <math.h>

#define N_NODES 50000
#define MP      50048  // padded to 128-row multiple for async-staged GEMM A reads
#define N_EDGES 800000
#define F_IN    165
#define KPAD1   192   // F_IN padded to multiple of 32
#define D1      256   // 8 heads x 32
#define D3      128   // 4 heads x 32
#define CAP     64    // max edges per node (Poisson(16): P(deg>=64) ~ 1e-19)

typedef __attribute__((ext_vector_type(8))) short short8;   // 8 bf16 = 4 VGPRs
typedef __attribute__((ext_vector_type(4))) float floatx4;
typedef __attribute__((ext_vector_type(2))) float floatx2;

__device__ __forceinline__ float bflo(unsigned u) { return __uint_as_float(u << 16); }
__device__ __forceinline__ float bfhi(unsigned u) { return __uint_as_float(u & 0xffff0000u); }

// packed-fp32 scale-accumulate: 8 bf16 lanes -> 4 v_pk_fma_f32
__device__ __forceinline__ void fma8p(floatx2* a, float wgt, const uint4& v) {
    floatx2 w2; w2.x = wgt; w2.y = wgt;
    floatx2 p;
    p.x = bflo(v.x); p.y = bfhi(v.x); a[0] += w2 * p;
    p.x = bflo(v.y); p.y = bfhi(v.y); a[1] += w2 * p;
    p.x = bflo(v.z); p.y = bfhi(v.z); a[2] += w2 * p;
    p.x = bflo(v.w); p.y = bfhi(v.w); a[3] += w2 * p;
}

#if defined(__has_builtin)
#if __has_builtin(__builtin_amdgcn_global_load_lds)
#define HAS_GLL 1
#endif
#endif

__device__ __forceinline__ void gload16(const void* g, void* lds) {
#ifdef HAS_GLL
    __builtin_amdgcn_global_load_lds(
        (const __attribute__((address_space(1))) unsigned*)g,
        (__attribute__((address_space(3))) unsigned*)lds, 16, 0, 0);
#else
    *(int4*)lds = *(const int4*)g;
#endif
}

// ---------- fused prep + degree histogram ----------
__global__ void prep_hist(const int* __restrict__ ei, int* __restrict__ deg,
                          const float* __restrict__ x, __hip_bfloat16* __restrict__ xb,
                          const float* __restrict__ W1, const float* __restrict__ skW,
                          const float* __restrict__ a1s, const float* __restrict__ a1d,
                          __hip_bfloat16* __restrict__ Bt1,
                          const float* __restrict__ W2,
                          const float* __restrict__ a2s, const float* __restrict__ a2d,
                          __hip_bfloat16* __restrict__ Bt2,
                          const float* __restrict__ W3,
                          const float* __restrict__ a3s, const float* __restrict__ a3d,
                          __hip_bfloat16* __restrict__ Bt3)
{
    long long gidx = (long long)blockIdx.x * 256 + threadIdx.x;
    if (gidx < N_EDGES) {
        atomicAdd(&deg[ei[N_EDGES + gidx]], 1);
        return;
    }
    long long idx = gidx - N_EDGES;
    const long long S0 = (long long)MP * KPAD1;          // xb
    const long long S1 = S0 + 256 * KPAD1;               // Wt1 rows
    const long long S2 = S1 + 128 * KPAD1;               // skWt rows
    const long long S3 = S2 + 16 * KPAD1;                // Wa1 rows
    const long long S4 = S3 + 256 * D1;                  // Wt2 rows
    const long long S5 = S4 + 16 * D1;                   // Wa2 rows
    const long long S6 = S5 + 128 * D1;                  // Wt3 rows
    const long long S7 = S6 + 8 * D1;                    // Wa3 rows
    if (idx < S0) {
        const int m = idx / KPAD1, k = idx - (long long)m * KPAD1;
        xb[idx] = __float2bfloat16((k < F_IN && m < N_NODES) ? x[(size_t)m * F_IN + k] : 0.f);
    } else if (idx < S1) {
        const long long i = idx - S0;
        const int n = i / KPAD1, k = i - (long long)n * KPAD1;
        Bt1[(size_t)n * KPAD1 + k] = __float2bfloat16((k < F_IN) ? W1[(size_t)k * D1 + n] : 0.f);
    } else if (idx < S2) {
        const long long i = idx - S1;
        const int n = i / KPAD1, k = i - (long long)n * KPAD1;
        Bt1[(size_t)(256 + n) * KPAD1 + k] =
            __float2bfloat16((k < F_IN) ? skW[(size_t)k * D3 + n] : 0.f);
    } else if (idx < S3) {
        const long long i = idx - S2;
        const int r = i / KPAD1, k = i - (long long)r * KPAD1;   // r: 0-7 src, 8-15 dst
        const int hh = r & 7;
        const float* av = (r < 8) ? a1s : a1d;
        float s = 0.f;
        if (k < F_IN)
#pragma unroll
            for (int d = 0; d < 32; ++d) s += W1[(size_t)k * D1 + hh * 32 + d] * av[hh * 32 + d];
        Bt1[(size_t)(384 + r) * KPAD1 + k] = __float2bfloat16(s);
    } else if (idx < S4) {
        const long long i = idx - S3;
        const int n = i / D1, k = i - (long long)n * D1;
        Bt2[(size_t)n * D1 + k] = __float2bfloat16(W2[(size_t)k * D1 + n]);
    } else if (idx < S5) {
        const long long i = idx - S4;
        const int r = i / D1, k = i - (long long)r * D1;
        const int hh = r & 7;
        const float* av = (r < 8) ? a2s : a2d;
        float s = 0.f;
#pragma unroll
        for (int d = 0; d < 32; ++d) s += W2[(size_t)k * D1 + hh * 32 + d] * av[hh * 32 + d];
        Bt2[(size_t)(256 + r) * D1 + k] = __float2bfloat16(s);
    } else if (idx < S6) {
        const long long i = idx - S5;
        const int n = i / D1, k = i - (long long)n * D1;
        Bt3[(size_t)n * D1 + k] = __float2bfloat16(W3[(size_t)k * D3 + n]);
    } else if (idx < S7) {
        const long long i = idx - S6;
        const int r = i / D1, k = i - (long long)r * D1;
        const int hh = r & 3;
        const float* av = (r < 4) ? a3s : a3d;
        float s = 0.f;
#pragma unroll
        for (int d = 0; d < 32; ++d) s += W3[(size_t)k * D3 + hh * 32 + d] * av[hh * 32 + d];
        Bt3[(size_t)(128 + r) * D1 + k] = __float2bfloat16(s);
    }
}

// ---------- bf16 MFMA GEMM, async LDS staging, 2D grid (one n-tile per block) ----------
// launch_bounds(256,4): cap VGPR at 128 -> 4 waves/SIMD for latency hiding
// (R13 showed this kernel is barrier/latency-bound: VALU 9%, MFMA 3%, HBM 6%).
// Output columns: [0,Dh) -> Cb bf16; [Dh,Dh+Dx) -> Cx bf16 (+biasx);
// [Dh+Dx, Dh+Dx+H) -> asrc fp32; [.., +2H) -> adst fp32; >= NNlive discarded.
__global__ __launch_bounds__(256, 4) void gemm_bf16(
    const __hip_bfloat16* __restrict__ A, const __hip_bfloat16* __restrict__ Bt,
    const float* __restrict__ alphap,
    __hip_bfloat16* __restrict__ Cb, int Dh,
    __hip_bfloat16* __restrict__ Cx, const float* __restrict__ biasx, int Dx,
    float* __restrict__ asrc, float* __restrict__ adst, int H,
    int M, int Ka)
{
    __shared__ short As[128 * 32];
    __shared__ short Bs[128 * 32];
    const int t  = threadIdx.x;
    const int m0 = blockIdx.x * 128;
    const int n0 = blockIdx.y * 128;
    const int w  = t >> 6, l = t & 63;
    const int wy = w >> 1, wx = w & 1;
    const int lm = l & 15, quad = l >> 4;
    const float alpha = alphap ? alphap[0] : 1.f;
    const int NNlive = Dh + Dx + 2 * H;

    floatx4 acc[4][4] = {};

    const int ch0 = w * 128 + l;
    const int ch1 = ch0 + 64;
    const int r0a = ch0 >> 2, k0a = (ch0 & 3) * 8;
    const int r1a = ch1 >> 2, k1a = (ch1 & 3) * 8;

    for (int k0 = 0; k0 < Ka; k0 += 32) {
        gload16(A  + (size_t)(m0 + r0a) * Ka + k0 + k0a, &As[ch0 * 8]);
        gload16(A  + (size_t)(m0 + r1a) * Ka + k0 + k1a, &As[ch1 * 8]);
        gload16(Bt + (size_t)(n0 + r0a) * Ka + k0 + k0a, &Bs[ch0 * 8]);
        gload16(Bt + (size_t)(n0 + r1a) * Ka + k0 + k1a, &Bs[ch1 * 8]);
        __syncthreads();

        short8 af[4], bf[4];
#pragma unroll
        for (int i = 0; i < 4; ++i) {
            af[i] = *(const short8*)&As[(wy * 64 + i * 16 + lm) * 32 + quad * 8];
            bf[i] = *(const short8*)&Bs[(wx * 64 + i * 16 + lm) * 32 + quad * 8];
        }
#pragma unroll
        for (int mi = 0; mi < 4; ++mi)
#pragma unroll
            for (int ni = 0; ni < 4; ++ni)
                acc[mi][ni] = __builtin_amdgcn_mfma_f32_16x16x32_bf16(
                    af[mi], bf[ni], acc[mi][ni], 0, 0, 0);
        __syncthreads();
    }

    // epilogue: C/D layout col=lane&15, row=quad*4+reg
#pragma unroll
    for (int mi = 0; mi < 4; ++mi) {
#pragma unroll
        for (int r = 0; r < 4; ++r) {
            const int gm = m0 + wy * 64 + mi * 16 + quad * 4 + r;
            if (gm >= M) continue;
#pragma unroll
            for (int ni = 0; ni < 4; ++ni) {
                const int gn = n0 + wx * 64 + ni * 16 + lm;
                if (gn >= NNlive) continue;
                const float v = acc[mi][ni][r] * alpha;
                if (gn < Dh) {
                    Cb[(size_t)gm * Dh + gn] = __float2bfloat16(v);
                } else if (gn < Dh + Dx) {
                    Cx[(size_t)gm * Dx + gn - Dh] = __float2bfloat16(v + biasx[gn - Dh]);
                } else {
                    const int c = gn - Dh - Dx;
                    if (c < H) asrc[(size_t)gm * H + c] = v;
                    else       adst[(size_t)gm * H + c - H] = v;
                }
            }
        }
    }
}

// ---------- CSR build ----------
__global__ __launch_bounds__(1024) void scan_rowptr(const int* __restrict__ deg,
                                                    int* __restrict__ rowptr, int n)
{
    __shared__ int sums[1024];
    const int tid = threadIdx.x;
    const int chunk = (n + 1023) / 1024;
    const int lo = tid * chunk;
    const int hi = min(lo + chunk, n);
    int s = 0;
    for (int i = lo; i < hi; ++i) s += deg[i];
    sums[tid] = s;
    __syncthreads();
    for (int off = 1; off < 1024; off <<= 1) {
        int t = 0;
        if (tid >= off) t = sums[tid - off];
        __syncthreads();
        if (tid >= off) sums[tid] += t;
        __syncthreads();
    }
    int run = sums[tid] - s;
    for (int i = lo; i < hi; ++i) { rowptr[i] = run; run += deg[i]; }
    if (lo < n && hi == n) rowptr[n] = run;
}

__global__ void csr_fill(const int* __restrict__ ei, const int* __restrict__ rowptr,
                         int* __restrict__ cursor, int* __restrict__ csr_src, int E)
{
    const int e = blockIdx.x * blockDim.x + threadIdx.x;
    if (e >= E) return;
    const int dst = ei[E + e];
    const int pos = rowptr[dst] + atomicAdd(&cursor[dst], 1);
    csr_src[pos] = ei[e];
}

// ---------- fused GAT aggregation v9: wave/node, no-max softmax, 2 load streams ----------
// POST: 1 bias+BN+ELU -> bf16; 2 same + bf16 residual (in-place-safe) -> bf16;
//       3 final: +b3 +bf16 xinit -> FC(2) + log_softmax -> outF[N*2].
template <int HSH, int D, int POST>
__global__ __launch_bounds__(256) void gat_gather_v9(
    const __hip_bfloat16* __restrict__ h, const float* __restrict__ asrc,
    const float* __restrict__ adst, const int* __restrict__ rowptr,
    const int* __restrict__ csr_src, int selfloop,
    const float* __restrict__ bias, const float* __restrict__ g,
    const float* __restrict__ be, const float* __restrict__ mean,
    const float* __restrict__ var, const __hip_bfloat16* __restrict__ residB,
    const float* __restrict__ fcW, const float* __restrict__ fcb,
    float* __restrict__ outF, __hip_bfloat16* __restrict__ outB)
{
    constexpr int H    = 1 << HSH;
    constexpr int LPE  = D / 8;
    constexpr int EPW  = 64 / LPE;
    constexpr int SUBS = 64 >> HSH;
    constexpr int MAXJ = CAP / SUBS;

    const int w = threadIdx.x >> 6, l = threadIdx.x & 63;
    const int node = blockIdx.x * 4 + w;

    __shared__ float sW[4][CAP * H];
    __shared__ int   sSrc[4][CAP];

    const int r0  = rowptr[node];
    const int deg = rowptr[node + 1] - r0;
    const int tot = min(deg + selfloop, CAP);

    // ---- phase 1 (single pass): exp(leaky(logit)) -> sum -> pre-scaled weights ----
    const int hh  = l & (H - 1);
    const int sub = l >> HSH;
    const float ad = adst[node * H + hh];

    float ex[MAXJ];
    float sum = 0.f;
    {
        int nj = 0;
        for (int e = sub; e < tot; e += SUBS, ++nj) {
            const int s = (e < deg) ? csr_src[r0 + e] : node;
            if (hh == 0) sSrc[w][e] = s;
            float v = asrc[s * H + hh] + ad;
            v = v > 0.f ? v : 0.2f * v;
            ex[nj] = __expf(v);
            sum += ex[nj];
        }
    }
#pragma unroll
    for (int off = H; off < 64; off <<= 1) sum += __shfl_xor(sum, off);
    const float rs = 1.f / (sum + 1e-16f);
    {
        int nj = 0;
        for (int e = sub; e < tot; e += SUBS, ++nj)
            sW[w][e * H + hh] = ex[nj] * rs;
    }

    // ---- phase 2: weighted bf16 row gather, 2 streams, packed fp32 ----
    const int sw   = l / LPE;
    const int lo   = l % LPE;
    const int dimb = lo * 8;
    const int hh2  = dimb >> 5;
    floatx2 a0[4] = {}, a1[4] = {};

    for (int e = sw; e < tot; e += 2 * EPW) {
        const int e2  = e + EPW;
        const bool v2 = e2 < tot;
        const int sa = sSrc[w][e];
        const int sb = v2 ? sSrc[w][e2] : node;
        const float wa = sW[w][e * H + hh2];
        const float wb = v2 ? sW[w][e2 * H + hh2] : 0.f;
        const uint4 qa = *(const uint4*)&h[(size_t)sa * D + dimb];
        const uint4 qb = *(const uint4*)&h[(size_t)sb * D + dimb];
        fma8p(a0, wa, qa);
        fma8p(a1, wb, qb);
    }
    float acc[8];
#pragma unroll
    for (int v = 0; v < 4; ++v) {
        const floatx2 s2v = a0[v] + a1[v];
        acc[v * 2] = s2v.x; acc[v * 2 + 1] = s2v.y;
    }
#pragma unroll
    for (int off = LPE; off < 64; off <<= 1)
#pragma unroll
        for (int v = 0; v < 8; ++v) acc[v] += __shfl_xor(acc[v], off);

    // ---- epilogue ----
    if (POST == 3) {
        float v0 = 0.f, v1 = 0.f;
        if (l < LPE) {
            const uint4 rv = *(const uint4*)&residB[(size_t)node * D + dimb];
            const float rr[8] = {bflo(rv.x), bfhi(rv.x), bflo(rv.y), bfhi(rv.y),
                                 bflo(rv.z), bfhi(rv.z), bflo(rv.w), bfhi(rv.w)};
#pragma unroll
            for (int v = 0; v < 8; ++v) {
                const float val = acc[v] + bias[dimb + v] + rr[v];
                v0 += val * fcW[(dimb + v) * 2 + 0];
                v1 += val * fcW[(dimb + v) * 2 + 1];
            }
        }
#pragma unroll
        for (int off = 1; off < LPE; off <<= 1) {
            v0 += __shfl_xor(v0, off);
            v1 += __shfl_xor(v1, off);
        }
        if (l == 0) {
            const float l0 = v0 + fcb[0], l1 = v1 + fcb[1];
            const float m2 = fmaxf(l0, l1);
            const float lse = m2 + logf(__expf(l0 - m2) + __expf(l1 - m2));
            outF[node * 2 + 0] = l0 - lse;
            outF[node * 2 + 1] = l1 - lse;
        }
    } else {
        if (l < LPE) {
            float rr[8] = {};
            if (POST == 2) {
                const uint4 rv = *(const uint4*)&residB[(size_t)node * D + dimb];
                rr[0] = bflo(rv.x); rr[1] = bfhi(rv.x);
                rr[2] = bflo(rv.y); rr[3] = bfhi(rv.y);
                rr[4] = bflo(rv.z); rr[5] = bfhi(rv.z);
                rr[6] = bflo(rv.w); rr[7] = bfhi(rv.w);
            }
            __hip_bfloat16 rb[8];
#pragma unroll
            for (int v = 0; v < 8; ++v) {
                const int f = dimb + v;
                float vv = acc[v] + bias[f];
                vv = (vv - mean[f]) * rsqrtf(var[f] + 1e-5f) * g[f] + be[f];
                if (POST == 2) vv += rr[v];
                vv = vv > 0.f ? vv : (__expf(vv) - 1.f);
                rb[v] = __float2bfloat16(vv);
            }
            *(uint4*)&outB[(size_t)node * D + dimb] = *(uint4*)&rb[0];
        }
    }
}

extern "C" void kernel_launch(void* const* d_in, const int* in_sizes, int n_in,
                              void* d_out, int out_size, void* d_ws, size_t ws_size,
                              hipStream_t stream)
{
    const float* x    = (const float*)d_in[0];
    const int*   ei   = (const int*)  d_in[1];
    const float* W1   = (const float*)d_in[2];
    const float* a1s  = (const float*)d_in[3];
    const float* a1d  = (const float*)d_in[4];
    const float* b1   = (const float*)d_in[5];
    const float* g1   = (const float*)d_in[6];
    const float* be1  = (const float*)d_in[7];
    const float* m1   = (const float*)d_in[8];
    const float* v1   = (const float*)d_in[9];
    const float* W2   = (const float*)d_in[10];
    const float* a2s  = (const float*)d_in[11];
    const float* a2d  = (const float*)d_in[12];
    const float* b2   = (const float*)d_in[13];
    const float* g2   = (const float*)d_in[14];
    const float* be2  = (const float*)d_in[15];
    const float* m2   = (const float*)d_in[16];
    const float* v2   = (const float*)d_in[17];
    const float* W3   = (const float*)d_in[18];
    const float* a3s  = (const float*)d_in[19];
    const float* a3d  = (const float*)d_in[20];
    const float* b3   = (const float*)d_in[21];
    const float* fcW  = (const float*)d_in[22];
    const float* fcb  = (const float*)d_in[23];
    const float* skW  = (const float*)d_in[24];
    const float* skb  = (const float*)d_in[25];
    const float* temp = (const float*)d_in[26];

    float* out = (float*)d_out;

    const int N = N_NODES, E = N_EDGES;

    // workspace layout (float units)
    float* ws = (float*)d_ws;
    size_t o = 0;
    float* asrc  = ws + o;  o += (size_t)N * 8;
    float* adst  = ws + o;  o += (size_t)N * 8;
    int* rowptr  = (int*)(ws + o);  o += N + 1;
    o = (o + 3) & ~(size_t)3;
    int* csr_src = (int*)(ws + o);  o += E;
    o = (o + 3) & ~(size_t)3;
    __hip_bfloat16* xb     = (__hip_bfloat16*)(ws + o); o += (size_t)MP * KPAD1 / 2;
    __hip_bfloat16* bufCb  = (__hip_bfloat16*)(ws + o); o += (size_t)MP * D1 / 2;  // layer input / residual
    __hip_bfloat16* hb     = (__hip_bfloat16*)(ws + o); o += (size_t)N * D1 / 2;   // GEMM out
    __hip_bfloat16* xinitB = (__hip_bfloat16*)(ws + o); o += (size_t)N * D3 / 2;   // skip branch bf16
    __hip_bfloat16* Bt1    = (__hip_bfloat16*)(ws + o); o += (size_t)512 * KPAD1 / 2;
    __hip_bfloat16* Bt2    = (__hip_bfloat16*)(ws + o); o += (size_t)384 * D1 / 2;
    __hip_bfloat16* Bt3    = (__hip_bfloat16*)(ws + o); o += (size_t)256 * D1 / 2;
    int* deg    = (int*)hb;        // alias: CSR build finishes before hb's first write
    int* cursor = deg + N;

    const int MT128 = MP / 128;      // 391

    // ---- CSR build + fused prep ----
    hipMemsetAsync(deg, 0, (size_t)2 * N * sizeof(int), stream);
    {
        const long long tote = (long long)E + (long long)MP * KPAD1 +
                               (256 + 128 + 16) * (long long)KPAD1 +
                               (256 + 16 + 128 + 8) * (long long)D1;
        prep_hist<<<(tote + 255) / 256, 256, 0, stream>>>(
            ei, deg, x, xb, W1, skW, a1s, a1d, Bt1, W2, a2s, a2d, Bt2, W3, a3s, a3d, Bt3);
    }
    scan_rowptr<<<1, 1024, 0, stream>>>(deg, rowptr, N);
    csr_fill<<<(E + 255) / 256, 256, 0, stream>>>(ei, rowptr, cursor, csr_src, E);

    // ================= Layer 1 GEMM: h1 | xinit | asrc | adst (live cols = 400) =================
    gemm_bf16<<<dim3(MT128, 4), 256, 0, stream>>>(xb, Bt1, nullptr,
                                                  hb, D1, xinitB, skb, D3,
                                                  asrc, adst, 8, N, KPAD1);
    gat_gather_v9<3, D1, 1><<<N / 4, 256, 0, stream>>>(hb, asrc, adst, rowptr, csr_src, 0,
                                                       b1, g1, be1, m1, v1, nullptr, nullptr, nullptr,
                                                       nullptr, bufCb);

    // ================= Layer 2 GEMM: h2 | asrc | adst (live cols = 272) =================
    gemm_bf16<<<dim3(MT128, 3), 256, 0, stream>>>(bufCb, Bt2, nullptr,
                                                  hb, D1, nullptr, nullptr, 0,
                                                  asrc, adst, 8, N, D1);
    gat_gather_v9<3, D1, 2><<<N / 4, 256, 0, stream>>>(hb, asrc, adst, rowptr, csr_src, 1,
                                                       b2, g2, be2, m2, v2, bufCb, nullptr, nullptr,
                                                       nullptr, bufCb);

    // ================= Layer 3 GEMM (temp-scaled): h3 | asrc | adst (live = 136) =================
    gemm_bf16<<<dim3(MT128, 2), 256, 0, stream>>>(bufCb, Bt3, temp,
                                                  hb, D3, nullptr, nullptr, 0,
                                                  asrc, adst, 4, N, D1);
    gat_gather_v9<2, D3, 3><<<N / 4, 256, 0, stream>>>(hb, asrc, adst, rowptr, csr_src, 1,
                                                       b3, nullptr, nullptr, nullptr, nullptr, xinitB,
                                                       fcW, fcb, out, nullptr);

    (void)in_sizes; (void)n_in; (void)out_size; (void)ws_size;
}

// Round 15
// 528.634 us; speedup vs baseline: 1.3011x; 1.1431x over previous
//
#include <hip/hip_runtime.h>
#include <hip/hip_bf16.h>
#include <math.h>

#define N_NODES 50000
#define MP      50048  // padded to 128-row multiple for async-staged GEMM A reads
#define N_EDGES 800000
#define F_IN    165
#define KPAD1   192   // F_IN padded to multiple of 32
#define D1      256   // 8 heads x 32
#define D3      128   // 4 heads x 32
#define CAP     64    // max edges per node (Poisson(16): P(deg>=64) ~ 1e-19)
#define SCB     512   // scan block size

typedef __attribute__((ext_vector_type(8))) short short8;   // 8 bf16 = 4 VGPRs
typedef __attribute__((ext_vector_type(4))) float floatx4;
typedef __attribute__((ext_vector_type(2))) float floatx2;

__device__ __forceinline__ float bflo(unsigned u) { return __uint_as_float(u << 16); }
__device__ __forceinline__ float bfhi(unsigned u) { return __uint_as_float(u & 0xffff0000u); }

// packed-fp32 scale-accumulate: 8 bf16 lanes -> 4 v_pk_fma_f32
__device__ __forceinline__ void fma8p(floatx2* a, float wgt, const uint4& v) {
    floatx2 w2; w2.x = wgt; w2.y = wgt;
    floatx2 p;
    p.x = bflo(v.x); p.y = bfhi(v.x); a[0] += w2 * p;
    p.x = bflo(v.y); p.y = bfhi(v.y); a[1] += w2 * p;
    p.x = bflo(v.z); p.y = bfhi(v.z); a[2] += w2 * p;
    p.x = bflo(v.w); p.y = bfhi(v.w); a[3] += w2 * p;
}

#if defined(__has_builtin)
#if __has_builtin(__builtin_amdgcn_global_load_lds)
#define HAS_GLL 1
#endif
#endif

__device__ __forceinline__ void gload16(const void* g, void* lds) {
#ifdef HAS_GLL
    __builtin_amdgcn_global_load_lds(
        (const __attribute__((address_space(1))) unsigned*)g,
        (__attribute__((address_space(3))) unsigned*)lds, 16, 0, 0);
#else
    *(int4*)lds = *(const int4*)g;
#endif
}

// ---------- fused prep + degree histogram ----------
__global__ void prep_hist(const int* __restrict__ ei, int* __restrict__ deg,
                          const float* __restrict__ x, __hip_bfloat16* __restrict__ xb,
                          const float* __restrict__ W1, const float* __restrict__ skW,
                          const float* __restrict__ a1s, const float* __restrict__ a1d,
                          __hip_bfloat16* __restrict__ Bt1,
                          const float* __restrict__ W2,
                          const float* __restrict__ a2s, const float* __restrict__ a2d,
                          __hip_bfloat16* __restrict__ Bt2,
                          const float* __restrict__ W3,
                          const float* __restrict__ a3s, const float* __restrict__ a3d,
                          __hip_bfloat16* __restrict__ Bt3)
{
    long long gidx = (long long)blockIdx.x * 256 + threadIdx.x;
    if (gidx < N_EDGES) {
        atomicAdd(&deg[ei[N_EDGES + gidx]], 1);
        return;
    }
    long long idx = gidx - N_EDGES;
    const long long S0 = (long long)MP * KPAD1;          // xb
    const long long S1 = S0 + 256 * KPAD1;               // Wt1 rows
    const long long S2 = S1 + 128 * KPAD1;               // skWt rows
    const long long S3 = S2 + 16 * KPAD1;                // Wa1 rows
    const long long S4 = S3 + 256 * D1;                  // Wt2 rows
    const long long S5 = S4 + 16 * D1;                   // Wa2 rows
    const long long S6 = S5 + 128 * D1;                  // Wt3 rows
    const long long S7 = S6 + 8 * D1;                    // Wa3 rows
    if (idx < S0) {
        const int m = idx / KPAD1, k = idx - (long long)m * KPAD1;
        xb[idx] = __float2bfloat16((k < F_IN && m < N_NODES) ? x[(size_t)m * F_IN + k] : 0.f);
    } else if (idx < S1) {
        const long long i = idx - S0;
        const int n = i / KPAD1, k = i - (long long)n * KPAD1;
        Bt1[(size_t)n * KPAD1 + k] = __float2bfloat16((k < F_IN) ? W1[(size_t)k * D1 + n] : 0.f);
    } else if (idx < S2) {
        const long long i = idx - S1;
        const int n = i / KPAD1, k = i - (long long)n * KPAD1;
        Bt1[(size_t)(256 + n) * KPAD1 + k] =
            __float2bfloat16((k < F_IN) ? skW[(size_t)k * D3 + n] : 0.f);
    } else if (idx < S3) {
        const long long i = idx - S2;
        const int r = i / KPAD1, k = i - (long long)r * KPAD1;   // r: 0-7 src, 8-15 dst
        const int hh = r & 7;
        const float* av = (r < 8) ? a1s : a1d;
        float s = 0.f;
        if (k < F_IN)
#pragma unroll
            for (int d = 0; d < 32; ++d) s += W1[(size_t)k * D1 + hh * 32 + d] * av[hh * 32 + d];
        Bt1[(size_t)(384 + r) * KPAD1 + k] = __float2bfloat16(s);
    } else if (idx < S4) {
        const long long i = idx - S3;
        const int n = i / D1, k = i - (long long)n * D1;
        Bt2[(size_t)n * D1 + k] = __float2bfloat16(W2[(size_t)k * D1 + n]);
    } else if (idx < S5) {
        const long long i = idx - S4;
        const int r = i / D1, k = i - (long long)r * D1;
        const int hh = r & 7;
        const float* av = (r < 8) ? a2s : a2d;
        float s = 0.f;
#pragma unroll
        for (int d = 0; d < 32; ++d) s += W2[(size_t)k * D1 + hh * 32 + d] * av[hh * 32 + d];
        Bt2[(size_t)(256 + r) * D1 + k] = __float2bfloat16(s);
    } else if (idx < S6) {
        const long long i = idx - S5;
        const int n = i / D1, k = i - (long long)n * D1;
        Bt3[(size_t)n * D1 + k] = __float2bfloat16(W3[(size_t)k * D3 + n]);
    } else if (idx < S7) {
        const long long i = idx - S6;
        const int r = i / D1, k = i - (long long)r * D1;
        const int hh = r & 3;
        const float* av = (r < 4) ? a3s : a3d;
        float s = 0.f;
#pragma unroll
        for (int d = 0; d < 32; ++d) s += W3[(size_t)k * D3 + hh * 32 + d] * av[hh * 32 + d];
        Bt3[(size_t)(128 + r) * D1 + k] = __float2bfloat16(s);
    }
}

// ---------- bf16 MFMA GEMM: double-buffered async staging, ONE barrier per k-iter ----------
// R13 evidence: this kernel is barrier/latency-bound (MFMA 3%, VALU 9%, HBM 6%).
// dbuf: barrier drains loads issued one full compute-phase earlier; tile k+1 loads
// are issued right after the barrier so they fly during compute of tile k.
__global__ __launch_bounds__(256, 4) void gemm_bf16(
    const __hip_bfloat16* __restrict__ A, const __hip_bfloat16* __restrict__ Bt,
    const float* __restrict__ alphap,
    __hip_bfloat16* __restrict__ Cb, int Dh,
    __hip_bfloat16* __restrict__ Cx, const float* __restrict__ biasx, int Dx,
    float* __restrict__ asrc, float* __restrict__ adst, int H,
    int M, int Ka)
{
    __shared__ short As[2][128 * 32];
    __shared__ short Bs[2][128 * 32];
    const int t  = threadIdx.x;
    const int m0 = blockIdx.x * 128;
    const int n0 = blockIdx.y * 128;
    const int w  = t >> 6, l = t & 63;
    const int wy = w >> 1, wx = w & 1;
    const int lm = l & 15, quad = l >> 4;
    const float alpha = alphap ? alphap[0] : 1.f;
    const int NNlive = Dh + Dx + 2 * H;
    const int KT = Ka >> 5;

    floatx4 acc[4][4] = {};

    const int ch0 = w * 128 + l;
    const int ch1 = ch0 + 64;
    const int r0a = ch0 >> 2, k0a = (ch0 & 3) * 8;
    const int r1a = ch1 >> 2, k1a = (ch1 & 3) * 8;

    // prologue: stage tile 0 into buffer 0
    gload16(A  + (size_t)(m0 + r0a) * Ka + k0a, &As[0][ch0 * 8]);
    gload16(A  + (size_t)(m0 + r1a) * Ka + k1a, &As[0][ch1 * 8]);
    gload16(Bt + (size_t)(n0 + r0a) * Ka + k0a, &Bs[0][ch0 * 8]);
    gload16(Bt + (size_t)(n0 + r1a) * Ka + k1a, &Bs[0][ch1 * 8]);

    for (int kt = 0; kt < KT; ++kt) {
        __syncthreads();   // drains tile-kt loads; guarantees tile-(kt-1) reads done
        const int cur = kt & 1;
        if (kt + 1 < KT) {
            const int nxt = cur ^ 1;
            const int k0 = (kt + 1) << 5;
            gload16(A  + (size_t)(m0 + r0a) * Ka + k0 + k0a, &As[nxt][ch0 * 8]);
            gload16(A  + (size_t)(m0 + r1a) * Ka + k0 + k1a, &As[nxt][ch1 * 8]);
            gload16(Bt + (size_t)(n0 + r0a) * Ka + k0 + k0a, &Bs[nxt][ch0 * 8]);
            gload16(Bt + (size_t)(n0 + r1a) * Ka + k0 + k1a, &Bs[nxt][ch1 * 8]);
        }

        short8 af[4], bf[4];
#pragma unroll
        for (int i = 0; i < 4; ++i) {
            af[i] = *(const short8*)&As[cur][(wy * 64 + i * 16 + lm) * 32 + quad * 8];
            bf[i] = *(const short8*)&Bs[cur][(wx * 64 + i * 16 + lm) * 32 + quad * 8];
        }
#pragma unroll
        for (int mi = 0; mi < 4; ++mi)
#pragma unroll
            for (int ni = 0; ni < 4; ++ni)
                acc[mi][ni] = __builtin_amdgcn_mfma_f32_16x16x32_bf16(
                    af[mi], bf[ni], acc[mi][ni], 0, 0, 0);
    }

    // epilogue: C/D layout col=lane&15, row=quad*4+reg
#pragma unroll
    for (int mi = 0; mi < 4; ++mi) {
#pragma unroll
        for (int r = 0; r < 4; ++r) {
            const int gm = m0 + wy * 64 + mi * 16 + quad * 4 + r;
            if (gm >= M) continue;
#pragma unroll
            for (int ni = 0; ni < 4; ++ni) {
                const int gn = n0 + wx * 64 + ni * 16 + lm;
                if (gn >= NNlive) continue;
                const float v = acc[mi][ni][r] * alpha;
                if (gn < Dh) {
                    Cb[(size_t)gm * Dh + gn] = __float2bfloat16(v);
                } else if (gn < Dh + Dx) {
                    Cx[(size_t)gm * Dx + gn - Dh] = __float2bfloat16(v + biasx[gn - Dh]);
                } else {
                    const int c = gn - Dh - Dx;
                    if (c < H) asrc[(size_t)gm * H + c] = v;
                    else       adst[(size_t)gm * H + c - H] = v;
                }
            }
        }
    }
}

// ---------- CSR build: parallel 3-stage exclusive scan ----------
__global__ __launch_bounds__(SCB) void scan_blk(const int* __restrict__ deg,
                                                int* __restrict__ rowptr,
                                                int* __restrict__ part, int n)
{
    __shared__ int s[SCB];
    const int i = blockIdx.x * SCB + threadIdx.x;
    const int v = (i < n) ? deg[i] : 0;
    s[threadIdx.x] = v;
    __syncthreads();
    for (int off = 1; off < SCB; off <<= 1) {
        int tv = 0;
        if (threadIdx.x >= off) tv = s[threadIdx.x - off];
        __syncthreads();
        s[threadIdx.x] += tv;
        __syncthreads();
    }
    if (i < n) rowptr[i] = s[threadIdx.x] - v;   // exclusive within block
    if (threadIdx.x == SCB - 1) part[blockIdx.x] = s[SCB - 1];
}

__global__ __launch_bounds__(128) void scan_part(int* __restrict__ part, int nb)
{
    __shared__ int s[128];
    const int v = (threadIdx.x < nb) ? part[threadIdx.x] : 0;
    s[threadIdx.x] = v;
    __syncthreads();
    for (int off = 1; off < 128; off <<= 1) {
        int tv = 0;
        if (threadIdx.x >= off) tv = s[threadIdx.x - off];
        __syncthreads();
        s[threadIdx.x] += tv;
        __syncthreads();
    }
    if (threadIdx.x < nb) part[threadIdx.x] = s[threadIdx.x] - v;   // exclusive
}

__global__ __launch_bounds__(SCB) void scan_add(int* __restrict__ rowptr,
                                                const int* __restrict__ part, int n)
{
    const int i = blockIdx.x * SCB + threadIdx.x;
    if (i < n) rowptr[i] += part[blockIdx.x];
    if (i == 0) rowptr[n] = N_EDGES;   // total degree is constant
}

__global__ void csr_fill(const int* __restrict__ ei, const int* __restrict__ rowptr,
                         int* __restrict__ cursor, int* __restrict__ csr_src, int E)
{
    const int e = blockIdx.x * blockDim.x + threadIdx.x;
    if (e >= E) return;
    const int dst = ei[E + e];
    const int pos = rowptr[dst] + atomicAdd(&cursor[dst], 1);
    csr_src[pos] = ei[e];
}

// ---------- fused GAT aggregation v9: wave/node, no-max softmax, 2 load streams ----------
// POST: 1 bias+BN+ELU -> bf16; 2 same + bf16 residual (in-place-safe) -> bf16;
//       3 final: +b3 +bf16 xinit -> FC(2) + log_softmax -> outF[N*2].
template <int HSH, int D, int POST>
__global__ __launch_bounds__(256) void gat_gather_v9(
    const __hip_bfloat16* __restrict__ h, const float* __restrict__ asrc,
    const float* __restrict__ adst, const int* __restrict__ rowptr,
    const int* __restrict__ csr_src, int selfloop,
    const float* __restrict__ bias, const float* __restrict__ g,
    const float* __restrict__ be, const float* __restrict__ mean,
    const float* __restrict__ var, const __hip_bfloat16* __restrict__ residB,
    const float* __restrict__ fcW, const float* __restrict__ fcb,
    float* __restrict__ outF, __hip_bfloat16* __restrict__ outB)
{
    constexpr int H    = 1 << HSH;
    constexpr int LPE  = D / 8;
    constexpr int EPW  = 64 / LPE;
    constexpr int SUBS = 64 >> HSH;
    constexpr int MAXJ = CAP / SUBS;

    const int w = threadIdx.x >> 6, l = threadIdx.x & 63;
    const int node = blockIdx.x * 4 + w;

    __shared__ float sW[4][CAP * H];
    __shared__ int   sSrc[4][CAP];

    const int r0  = rowptr[node];
    const int deg = rowptr[node + 1] - r0;
    const int tot = min(deg + selfloop, CAP);

    // ---- phase 1 (single pass): exp(leaky(logit)) -> sum -> pre-scaled weights ----
    const int hh  = l & (H - 1);
    const int sub = l >> HSH;
    const float ad = adst[node * H + hh];

    float ex[MAXJ];
    float sum = 0.f;
    {
        int nj = 0;
        for (int e = sub; e < tot; e += SUBS, ++nj) {
            const int s = (e < deg) ? csr_src[r0 + e] : node;
            if (hh == 0) sSrc[w][e] = s;
            float v = asrc[s * H + hh] + ad;
            v = v > 0.f ? v : 0.2f * v;
            ex[nj] = __expf(v);
            sum += ex[nj];
        }
    }
#pragma unroll
    for (int off = H; off < 64; off <<= 1) sum += __shfl_xor(sum, off);
    const float rs = 1.f / (sum + 1e-16f);
    {
        int nj = 0;
        for (int e = sub; e < tot; e += SUBS, ++nj)
            sW[w][e * H + hh] = ex[nj] * rs;
    }

    // ---- phase 2: weighted bf16 row gather, 2 streams, packed fp32 ----
    const int sw   = l / LPE;
    const int lo   = l % LPE;
    const int dimb = lo * 8;
    const int hh2  = dimb >> 5;
    floatx2 a0[4] = {}, a1[4] = {};

    for (int e = sw; e < tot; e += 2 * EPW) {
        const int e2  = e + EPW;
        const bool v2 = e2 < tot;
        const int sa = sSrc[w][e];
        const int sb = v2 ? sSrc[w][e2] : node;
        const float wa = sW[w][e * H + hh2];
        const float wb = v2 ? sW[w][e2 * H + hh2] : 0.f;
        const uint4 qa = *(const uint4*)&h[(size_t)sa * D + dimb];
        const uint4 qb = *(const uint4*)&h[(size_t)sb * D + dimb];
        fma8p(a0, wa, qa);
        fma8p(a1, wb, qb);
    }
    float acc[8];
#pragma unroll
    for (int v = 0; v < 4; ++v) {
        const floatx2 s2v = a0[v] + a1[v];
        acc[v * 2] = s2v.x; acc[v * 2 + 1] = s2v.y;
    }
#pragma unroll
    for (int off = LPE; off < 64; off <<= 1)
#pragma unroll
        for (int v = 0; v < 8; ++v) acc[v] += __shfl_xor(acc[v], off);

    // ---- epilogue ----
    if (POST == 3) {
        float v0 = 0.f, v1 = 0.f;
        if (l < LPE) {
            const uint4 rv = *(const uint4*)&residB[(size_t)node * D + dimb];
            const float rr[8] = {bflo(rv.x), bfhi(rv.x), bflo(rv.y), bfhi(rv.y),
                                 bflo(rv.z), bfhi(rv.z), bflo(rv.w), bfhi(rv.w)};
#pragma unroll
            for (int v = 0; v < 8; ++v) {
                const float val = acc[v] + bias[dimb + v] + rr[v];
                v0 += val * fcW[(dimb + v) * 2 + 0];
                v1 += val * fcW[(dimb + v) * 2 + 1];
            }
        }
#pragma unroll
        for (int off = 1; off < LPE; off <<= 1) {
            v0 += __shfl_xor(v0, off);
            v1 += __shfl_xor(v1, off);
        }
        if (l == 0) {
            const float l0 = v0 + fcb[0], l1 = v1 + fcb[1];
            const float m2 = fmaxf(l0, l1);
            const float lse = m2 + logf(__expf(l0 - m2) + __expf(l1 - m2));
            outF[node * 2 + 0] = l0 - lse;
            outF[node * 2 + 1] = l1 - lse;
        }
    } else {
        if (l < LPE) {
            float rr[8] = {};
            if (POST == 2) {
                const uint4 rv = *(const uint4*)&residB[(size_t)node * D + dimb];
                rr[0] = bflo(rv.x); rr[1] = bfhi(rv.x);
                rr[2] = bflo(rv.y); rr[3] = bfhi(rv.y);
                rr[4] = bflo(rv.z); rr[5] = bfhi(rv.z);
                rr[6] = bflo(rv.w); rr[7] = bfhi(rv.w);
            }
            __hip_bfloat16 rb[8];
#pragma unroll
            for (int v = 0; v < 8; ++v) {
                const int f = dimb + v;
                float vv = acc[v] + bias[f];
                vv = (vv - mean[f]) * rsqrtf(var[f] + 1e-5f) * g[f] + be[f];
                if (POST == 2) vv += rr[v];
                vv = vv > 0.f ? vv : (__expf(vv) - 1.f);
                rb[v] = __float2bfloat16(vv);
            }
            *(uint4*)&outB[(size_t)node * D + dimb] = *(uint4*)&rb[0];
        }
    }
}

extern "C" void kernel_launch(void* const* d_in, const int* in_sizes, int n_in,
                              void* d_out, int out_size, void* d_ws, size_t ws_size,
                              hipStream_t stream)
{
    const float* x    = (const float*)d_in[0];
    const int*   ei   = (const int*)  d_in[1];
    const float* W1   = (const float*)d_in[2];
    const float* a1s  = (const float*)d_in[3];
    const float* a1d  = (const float*)d_in[4];
    const float* b1   = (const float*)d_in[5];
    const float* g1   = (const float*)d_in[6];
    const float* be1  = (const float*)d_in[7];
    const float* m1   = (const float*)d_in[8];
    const float* v1   = (const float*)d_in[9];
    const float* W2   = (const float*)d_in[10];
    const float* a2s  = (const float*)d_in[11];
    const float* a2d  = (const float*)d_in[12];
    const float* b2   = (const float*)d_in[13];
    const float* g2   = (const float*)d_in[14];
    const float* be2  = (const float*)d_in[15];
    const float* m2   = (const float*)d_in[16];
    const float* v2   = (const float*)d_in[17];
    const float* W3   = (const float*)d_in[18];
    const float* a3s  = (const float*)d_in[19];
    const float* a3d  = (const float*)d_in[20];
    const float* b3   = (const float*)d_in[21];
    const float* fcW  = (const float*)d_in[22];
    const float* fcb  = (const float*)d_in[23];
    const float* skW  = (const float*)d_in[24];
    const float* skb  = (const float*)d_in[25];
    const float* temp = (const float*)d_in[26];

    float* out = (float*)d_out;

    const int N = N_NODES, E = N_EDGES;
    const int NB = (N + SCB - 1) / SCB;   // 98 scan blocks

    // workspace layout (float units)
    float* ws = (float*)d_ws;
    size_t o = 0;
    float* asrc  = ws + o;  o += (size_t)N * 8;
    float* adst  = ws + o;  o += (size_t)N * 8;
    int* rowptr  = (int*)(ws + o);  o += N + 1;
    o = (o + 3) & ~(size_t)3;
    int* csr_src = (int*)(ws + o);  o += E;
    o = (o + 3) & ~(size_t)3;
    int* part    = (int*)(ws + o);  o += 128;
    __hip_bfloat16* xb     = (__hip_bfloat16*)(ws + o); o += (size_t)MP * KPAD1 / 2;
    __hip_bfloat16* bufCb  = (__hip_bfloat16*)(ws + o); o += (size_t)MP * D1 / 2;  // layer input / residual
    __hip_bfloat16* hb     = (__hip_bfloat16*)(ws + o); o += (size_t)N * D1 / 2;   // GEMM out
    __hip_bfloat16* xinitB = (__hip_bfloat16*)(ws + o); o += (size_t)N * D3 / 2;   // skip branch bf16
    __hip_bfloat16* Bt1    = (__hip_bfloat16*)(ws + o); o += (size_t)512 * KPAD1 / 2;
    __hip_bfloat16* Bt2    = (__hip_bfloat16*)(ws + o); o += (size_t)384 * D1 / 2;
    __hip_bfloat16* Bt3    = (__hip_bfloat16*)(ws + o); o += (size_t)256 * D1 / 2;
    int* deg    = (int*)hb;        // alias: CSR build finishes before hb's first write
    int* cursor = deg + N;

    const int MT128 = MP / 128;      // 391

    // ---- CSR build + fused prep ----
    hipMemsetAsync(deg, 0, (size_t)2 * N * sizeof(int), stream);
    {
        const long long tote = (long long)E + (long long)MP * KPAD1 +
                               (256 + 128 + 16) * (long long)KPAD1 +
                               (256 + 16 + 128 + 8) * (long long)D1;
        prep_hist<<<(tote + 255) / 256, 256, 0, stream>>>(
            ei, deg, x, xb, W1, skW, a1s, a1d, Bt1, W2, a2s, a2d, Bt2, W3, a3s, a3d, Bt3);
    }
    scan_blk<<<NB, SCB, 0, stream>>>(deg, rowptr, part, N);
    scan_part<<<1, 128, 0, stream>>>(part, NB);
    scan_add<<<NB, SCB, 0, stream>>>(rowptr, part, N);
    csr_fill<<<(E + 255) / 256, 256, 0, stream>>>(ei, rowptr, cursor, csr_src, E);

    // ================= Layer 1 GEMM: h1 | xinit | asrc | adst (live cols = 400) =================
    gemm_bf16<<<dim3(MT128, 4), 256, 0, stream>>>(xb, Bt1, nullptr,
                                                  hb, D1, xinitB, skb, D3,
                                                  asrc, adst, 8, N, KPAD1);
    gat_gather_v9<3, D1, 1><<<N / 4, 256, 0, stream>>>(hb, asrc, adst, rowptr, csr_src, 0,
                                                       b1, g1, be1, m1, v1, nullptr, nullptr, nullptr,
                                                       nullptr, bufCb);

    // ================= Layer 2 GEMM: h2 | asrc | adst (live cols = 272) =================
    gemm_bf16<<<dim3(MT128, 3), 256, 0, stream>>>(bufCb, Bt2, nullptr,
                                                  hb, D1, nullptr, nullptr, 0,
                                                  asrc, adst, 8, N, D1);
    gat_gather_v9<3, D1, 2><<<N / 4, 256, 0, stream>>>(hb, asrc, adst, rowptr, csr_src, 1,
                                                       b2, g2, be2, m2, v2, bufCb, nullptr, nullptr,
                                                       nullptr, bufCb);

    // ================= Layer 3 GEMM (temp-scaled): h3 | asrc | adst (live = 136) =================
    gemm_bf16<<<dim3(MT128, 2), 256, 0, stream>>>(bufCb, Bt3, temp,
                                                  hb, D3, nullptr, nullptr, 0,
                                                  asrc, adst, 4, N, D1);
    gat_gather_v9<2, D3, 3><<<N / 4, 256, 0, stream>>>(hb, asrc, adst, rowptr, csr_src, 1,
                                                       b3, nullptr, nullptr, nullptr, nullptr, xinitB,
                                                       fcW, fcb, out, nullptr);

    (void)in_sizes; (void)n_in; (void)out_size; (void)ws_size;
}